// Round 10
// baseline (413.688 us; speedup 1.0000x reference)
//
#include <hip/hip_runtime.h>

typedef __bf16 bf16x8 __attribute__((ext_vector_type(8)));
typedef __bf16 bf16x4 __attribute__((ext_vector_type(4)));
typedef float  f32x4  __attribute__((ext_vector_type(4)));
typedef unsigned u32x4 __attribute__((ext_vector_type(4)));

constexpr int kHW = 2304;   // 48*48
constexpr int kC  = 512;

#if __has_builtin(__builtin_amdgcn_exp2f)
#define EXP2(x) __builtin_amdgcn_exp2f(x)
#else
#define EXP2(x) exp2f(x)
#endif

// async global->LDS, 16B per lane. gptr per-lane (base + lane*16B), lptr wave-uniform chunk base.
__device__ __forceinline__ void dma16(const __bf16* g, __bf16* l) {
    __builtin_amdgcn_global_load_lds(
        (const volatile __attribute__((address_space(1))) void*)g,
        (volatile __attribute__((address_space(3))) void*)l, 16, 0, 0);
}

// pack two f32 -> one u32 of 2 bf16 (RNE via compiler casts; m240: do not hand-write cvt_pk)
__device__ __forceinline__ unsigned pack2(float a, float b) {
    unsigned lo = (unsigned)__builtin_bit_cast(unsigned short, (__bf16)a);
    unsigned hi = (unsigned)__builtin_bit_cast(unsigned short, (__bf16)b);
    return (hi << 16) | lo;
}

__device__ __forceinline__ unsigned bp(int addr, unsigned v) {
    return (unsigned)__builtin_amdgcn_ds_bpermute(addr, (int)v);
}

// ---------------------------------------------------------------------------
// Packed-operand layouts for the projection GEMM (BK=32, stride 32, XOR-swz):
//   element (row, k) of a 32-k chunk lives at  row*32 + ((slot ^ (row&3))<<3) + j
//   where slot = (k&31)>>3, j = k&7. Swizzle applied at PACK time (inverse-
//   permuted source) so the linear global_load_lds DMA lands the swizzled
//   pattern in LDS and the b128 fragment reads are conflict-free.
// XT2h  [b][kb2=16][n 2304][32]
// Wqk2h [kb2=16][o 128][32]   (o<64 = Wq rows, o>=64 = Wk rows)
// Wvb2h [kb2=16][c 512][32]

// K0: MERGED pack kernel. Blocks [0,4608) do pack_x; blocks [4608,5632) do
// pack_weights.
__global__ void pack_all(const float* __restrict__ x, const float* __restrict__ Wq,
                         const float* __restrict__ Wk, const float* __restrict__ Wv,
                         __bf16* __restrict__ XT2h, __bf16* __restrict__ Wqk2h,
                         __bf16* __restrict__ Wvb2h) {
    int t = threadIdx.x;
    if (blockIdx.x >= 4608) {
        // ---- pack_weights path ----
        int idx = (blockIdx.x - 4608) * 256 + t;     // 0 .. 262143
        int o = idx >> 9, k = idx & 511;
        int kb2 = k >> 5, slot = (k & 31) >> 3, j = k & 7;
        int sl = (slot ^ (o & 3)) << 3;
        if (idx < 64 * 512) {
            Wqk2h[((size_t)kb2 * 128 + o) * 32 + sl + j]      = (__bf16)Wq[idx];
            Wqk2h[((size_t)kb2 * 128 + 64 + o) * 32 + sl + j] = (__bf16)Wk[idx];
        }
        if (idx < 512 * 512)
            Wvb2h[((size_t)kb2 * 512 + o) * 32 + sl + j] = (__bf16)Wv[idx];
        return;
    }
    // ---- pack_x path: x [B][C][HW] fp32 -> XT2h (c-inner, XOR-swz) ----
    __shared__ __bf16 tile[64][65];              // [c][n]
    int u = blockIdx.x;
    int n0 = (u % 36) * 64;
    int kblk = (u / 36) & 7;
    int b = u / 288;
    int c0 = kblk * 64;
    const float* xb = x + (size_t)b * kC * kHW;
#pragma unroll
    for (int rep = 0; rep < 16; ++rep) {
        int c_loc = rep * 4 + (t >> 6);
        int n_loc = t & 63;
        tile[c_loc][n_loc] = (__bf16)xb[(size_t)(c0 + c_loc) * kHW + n0 + n_loc];
    }
    __syncthreads();
#pragma unroll
    for (int rep = 0; rep < 2; ++rep) {
        int item = rep * 256 + t;                // 512 items = 64 n x 8 chunks
        int n_loc = item >> 3, chunk = item & 7;
        bf16x8 v;
#pragma unroll
        for (int j = 0; j < 8; ++j) v[j] = tile[chunk * 8 + j][n_loc];
        int h = chunk >> 2;                      // which 32-k half
        int slot = chunk & 3;
        int sl = (slot ^ (n_loc & 3)) << 3;      // (n0%4==0 so n&3 == n_loc&3)
        __bf16* dst = XT2h + (((size_t)b * 16 + kblk * 2 + h) * kHW + (n0 + n_loc)) * 32 + sl;
        *(bf16x4*)(dst)     = (bf16x4){v[0], v[1], v[2], v[3]};
        *(bf16x4*)(dst + 4) = (bf16x4){v[4], v[5], v[6], v[7]};
    }
}

// ---------------------------------------------------------------------------
// K2: QKV projections, DOUBLE-BUFFERED BK=32 pipeline (unchanged from R8).
__global__ __launch_bounds__(256, 2) void qkv_gemm(const __bf16* __restrict__ XT2h,
                                                   const __bf16* __restrict__ Wqk2h,
                                                   const __bf16* __restrict__ Wvb2h,
                                                   const float* __restrict__ bq,
                                                   const float* __restrict__ bk,
                                                   const float* __restrict__ bv,
                                                   __bf16* __restrict__ qbuf,
                                                   __bf16* __restrict__ kbuf,
                                                   __bf16* __restrict__ vbuf2) {
    __shared__ __align__(16) __bf16 A_lds[2][128 * 32];   // 2 x 8 KB
    __shared__ __align__(16) __bf16 B_lds[2][128 * 32];   // 2 x 8 KB
    int bid = blockIdx.x;                         // 1440 = 8 XCD * 180
    int work = (bid & 7) * 180 + (bid >> 3);
    int type = work % 5;
    int g = work / 5;                             // 0..287
    int r0 = (g % 18) * 128;
    int b = g / 18;
    int t = threadIdx.x, wave = t >> 6, lane = t & 63, quad = lane >> 4, l16 = lane & 15;
    int slot8 = ((quad ^ (l16 & 3)) << 3);        // swizzled 16B slot for frag reads

    f32x4 acc[8][2];
#pragma unroll
    for (int i = 0; i < 8; ++i)
#pragma unroll
        for (int j = 0; j < 2; ++j) acc[i][j] = (f32x4){0.f, 0.f, 0.f, 0.f};

    auto stage = [&](int kb2, int buf) {
        const __bf16* Asrc;
        const __bf16* Bsrc;
        if (type == 0) {
            Asrc = XT2h + (((size_t)b * 16 + kb2) * kHW + r0) * 32;
            Bsrc = Wqk2h + (size_t)kb2 * 128 * 32;
        } else {
            Asrc = Wvb2h + ((size_t)kb2 * 512 + (type - 1) * 128) * 32;
            Bsrc = XT2h + (((size_t)b * 16 + kb2) * kHW + r0) * 32;
        }
        for (int ch = wave; ch < 8; ch += 4) {
            dma16(Asrc + ch * 512 + lane * 8, &A_lds[buf][ch * 512]);
            dma16(Bsrc + ch * 512 + lane * 8, &B_lds[buf][ch * 512]);
        }
    };

    stage(0, 0);
    for (int kb2 = 0; kb2 < 16; ++kb2) {
        int buf = kb2 & 1;
        __syncthreads();                          // drain DMA(kb2); guard buf^1 reads
        if (kb2 + 1 < 16) stage(kb2 + 1, buf ^ 1);
        bf16x8 bfr[2];
#pragma unroll
        for (int ct = 0; ct < 2; ++ct)
            bfr[ct] = *(const bf16x8*)(&B_lds[buf][(wave * 32 + ct * 16 + l16) * 32 + slot8]);
#pragma unroll
        for (int rt = 0; rt < 8; ++rt) {
            bf16x8 a = *(const bf16x8*)(&A_lds[buf][(rt * 16 + l16) * 32 + slot8]);
#pragma unroll
            for (int ct = 0; ct < 2; ++ct)
                acc[rt][ct] = __builtin_amdgcn_mfma_f32_16x16x32_bf16(a, bfr[ct], acc[rt][ct], 0, 0, 0);
        }
    }

    if (type == 0) {
        constexpr float kLog2e = 1.4426950408889634f;
#pragma unroll
        for (int ct = 0; ct < 2; ++ct) {
            int o = wave * 32 + ct * 16 + l16;
            float bias = (o < 64) ? bq[o] : bk[o - 64];
            float scale = (o < 64) ? kLog2e : 1.0f;   // fold ln2 into Q
#pragma unroll
            for (int rt = 0; rt < 8; ++rt)
#pragma unroll
                for (int r = 0; r < 4; ++r) {
                    int n = r0 + rt * 16 + quad * 4 + r;
                    __bf16 val = (__bf16)((acc[rt][ct][r] + bias) * scale);
                    if (o < 64) {
                        qbuf[((size_t)b * kHW + n) * 64 + o] = val;
                    } else {
                        int d = o - 64;
                        int dsw = (((d >> 3) ^ (n & 7)) << 3) | (d & 7);
                        kbuf[(((size_t)b * 72 + (n >> 5)) * 32 + (n & 31)) * 64 + dsw] = val;
                    }
                }
        }
    } else {
#pragma unroll
        for (int rt = 0; rt < 8; ++rt)
#pragma unroll
            for (int r = 0; r < 4; ++r) {
                int c = (type - 1) * 128 + rt * 16 + quad * 4 + r;
                float bias = bv[c];
#pragma unroll
                for (int ct = 0; ct < 2; ++ct) {
                    int m = r0 + wave * 32 + ct * 16 + l16;
                    vbuf2[(((size_t)b * 72 + (m >> 5)) * 512 + c) * 40 + (m & 31)] = (__bf16)(acc[rt][ct][r] + bias);
                }
            }
    }
}

// ---------------------------------------------------------------------------
// K3: flash attention, n128 x c128, Tm=32, 4 waves x 32 rows, pipelined
// (R5/R8 mechanism) with IN-REGISTER P via ds_bpermute (known semantics:
// pull, v0 <- lane[addr>>2].v2).
// Derivation (matches the verified R8 LDS indexing): source lane (q_s,l16)
// holds m = mt*16 + q_s*4 + r in words p0=(r0,r1), p1=(r2,r3); PV A-frag dest
// lane (q_d,l16) needs m = q_d*8 + j, i.e. mt = q_d>>1, src quads
// qa=(q_d&1)*2 and qa+1, word order [qa.p0, qa.p1, qb.p0, qb.p1].
// addr_a = ((quad&1)<<5 | l16)<<2, addr_b = addr_a + 64; pull both mt regs,
// select with (quad>=2). No P_lds -> LDS 29,184 B; launch_bounds(256,4)
// caps regs safely (5 blocks/CU materialize if alloc <= 102).
__global__ __launch_bounds__(256, 4) void attn_kernel(const __bf16* __restrict__ qbuf,
                                                      const __bf16* __restrict__ kbuf,
                                                      const __bf16* __restrict__ vbuf2,
                                                      const float* __restrict__ x,
                                                      const float* __restrict__ gamma,
                                                      float* __restrict__ out) {
    __shared__ __align__(16) __bf16 K_lds[2][32 * 64];    //  8.0 KB
    __shared__ __align__(16) __bf16 V_lds[2][128 * 40];   // 20.0 KB
    __shared__ float rs_lds[128];                         //  0.5 KB

    int bid = blockIdx.x;                         // 1152 = 8 XCD * 144
    int work = (bid & 7) * 144 + (bid >> 3);
    int n0 = (work % 18) * 128;
    int pair = work / 18;                         // 0..63
    int c0 = (pair & 3) * 128;
    int b = pair >> 2;
    int t = threadIdx.x, wave = t >> 6, lane = t & 63, quad = lane >> 4, l16 = lane & 15;
    const __bf16* q_b    = qbuf + (size_t)b * kHW * 64;
    const __bf16* k_base = kbuf + (size_t)b * 72 * 32 * 64;

    // Q fragments (held all kernel): wave owns S rows 32*wave .. +31 (B-operand of swapped QK^T)
    bf16x8 aq[2][2];
#pragma unroll
    for (int rt2 = 0; rt2 < 2; ++rt2)
#pragma unroll
        for (int dk = 0; dk < 2; ++dk)
            aq[rt2][dk] = *(const bf16x8*)(q_b + (size_t)(n0 + wave * 32 + rt2 * 16 + l16) * 64 + dk * 32 + quad * 8);

    // acc[rt2][ct]: n = n0 + 32*wave + rt2*16 + quad*4 + r,  c = c0 + ct*16 + l16
    f32x4 acc[2][8];
#pragma unroll
    for (int i = 0; i < 2; ++i)
#pragma unroll
        for (int j = 0; j < 8; ++j) acc[i][j] = (f32x4){0.f, 0.f, 0.f, 0.f};
    float rsum[2] = {0.f, 0.f};
    bf16x8 pf[2];   // P(i) fragments, materialized one body ahead

    auto issue_K = [&](int i, int buf) {
        const __bf16* ks = k_base + (size_t)i * 32 * 64;                      // 4 KB tile
        dma16(ks + wave * 512 + lane * 8, &K_lds[buf][wave * 512]);
    };
    auto issue_V = [&](int i, int buf) {
        const __bf16* vs = vbuf2 + (((size_t)b * 72 + i) * 512 + c0) * 40;    // 10 KB tile
        for (int ch = wave; ch < 10; ch += 4)
            dma16(vs + ch * 512 + lane * 8, &V_lds[buf][ch * 512]);
    };
    // QK^T(j) from K_lds[j&1] -> exp2 -> pf regs (in-register P via bpermute)
    auto qk_phase = [&](int j) {
        int kb_ = j & 1;
        unsigned pk[2][2][2];   // [rt2][mt][word], all-constant indices after unroll
#pragma unroll
        for (int mt = 0; mt < 2; ++mt) {
            int row = mt * 16 + l16;
            int sw = (row & 7) << 3;
            bf16x8 kf0 = *(const bf16x8*)(&K_lds[kb_][row * 64 + ((quad * 8) ^ sw)]);
            bf16x8 kf1 = *(const bf16x8*)(&K_lds[kb_][row * 64 + ((32 + quad * 8) ^ sw)]);
#pragma unroll
            for (int rt2 = 0; rt2 < 2; ++rt2) {
                f32x4 s = (f32x4){0.f, 0.f, 0.f, 0.f};
                s = __builtin_amdgcn_mfma_f32_16x16x32_bf16(kf0, aq[rt2][0], s, 0, 0, 0);
                s = __builtin_amdgcn_mfma_f32_16x16x32_bf16(kf1, aq[rt2][1], s, 0, 0, 0);
                float e0 = EXP2(s[0]), e1 = EXP2(s[1]), e2 = EXP2(s[2]), e3 = EXP2(s[3]);
                rsum[rt2] += (e0 + e1) + (e2 + e3);
                pk[rt2][mt][0] = pack2(e0, e1);
                pk[rt2][mt][1] = pack2(e2, e3);
            }
        }
        // cross-quad exchange: dest (q_d,l16) pulls from src lanes
        // (qa,l16),(qa+1,l16), qa=(q_d&1)*2; selects mt = q_d>>1.
        int addr_a = (((quad & 1) << 5) | l16) << 2;
        int addr_b = addr_a + 64;
        bool hi = quad >= 2;
#pragma unroll
        for (int rt2 = 0; rt2 < 2; ++rt2) {
            unsigned a0 = bp(addr_a, pk[rt2][0][0]);
            unsigned b0 = bp(addr_a, pk[rt2][1][0]);
            unsigned a1 = bp(addr_a, pk[rt2][0][1]);
            unsigned b1 = bp(addr_a, pk[rt2][1][1]);
            unsigned a2 = bp(addr_b, pk[rt2][0][0]);
            unsigned b2 = bp(addr_b, pk[rt2][1][0]);
            unsigned a3 = bp(addr_b, pk[rt2][0][1]);
            unsigned b3 = bp(addr_b, pk[rt2][1][1]);
            u32x4 w = (u32x4){hi ? b0 : a0, hi ? b1 : a1, hi ? b2 : a2, hi ? b3 : a3};
            pf[rt2] = __builtin_bit_cast(bf16x8, w);
        }
    };

    // prologue: stage K(0),V(0),K(1); materialize P(0)
    issue_K(0, 0);
    issue_V(0, 0);
    issue_K(1, 1);
    __syncthreads();            // drain prologue DMAs
    qk_phase(0);

    for (int i = 0; i < 72; ++i) {
        __syncthreads();        // drains DMAs issued last body; guards buffer reuse
        if (i + 2 < 72) issue_K(i + 2, i & 1);          // K(i)'s old slot
        if (i + 1 < 72) issue_V(i + 1, (i + 1) & 1);    // V(i-1)'s old slot

        // PV(i): 16 independent MFMAs on pf (regs) x V(i) -- overlaps the
        // QK(i+1)+exp chain below (compiler-scheduled, separate pipes).
        __builtin_amdgcn_s_setprio(1);
#pragma unroll
        for (int ct = 0; ct < 8; ++ct) {
            bf16x8 vf = *(const bf16x8*)(&V_lds[i & 1][(ct * 16 + l16) * 40 + quad * 8]);
            acc[0][ct] = __builtin_amdgcn_mfma_f32_16x16x32_bf16(pf[0], vf, acc[0][ct], 0, 0, 0);
            acc[1][ct] = __builtin_amdgcn_mfma_f32_16x16x32_bf16(pf[1], vf, acc[1][ct], 0, 0, 0);
        }
        __builtin_amdgcn_s_setprio(0);

        // QK^T(i+1) -> exp -> pf (next body's A-operand)
        if (i + 1 < 72) qk_phase(i + 1);
    }

    // rowsum: per-lane partial covers quad m-slices; reduce across quads.
#pragma unroll
    for (int rt2 = 0; rt2 < 2; ++rt2) {
        float v = rsum[rt2];
        v += __shfl_xor(v, 16);
        v += __shfl_xor(v, 32);
        if (quad == 0) rs_lds[wave * 32 + rt2 * 16 + l16] = v;
    }
    __syncthreads();

    float g = gamma[0];
    const float* x_b = x + (size_t)b * kC * kHW;
    float* out_b = out + (size_t)b * kC * kHW;
#pragma unroll
    for (int rt2 = 0; rt2 < 2; ++rt2) {
        float inv[4];
#pragma unroll
        for (int r = 0; r < 4; ++r) inv[r] = 1.f / rs_lds[wave * 32 + rt2 * 16 + quad * 4 + r];
#pragma unroll
        for (int ct = 0; ct < 8; ++ct) {
            int c = c0 + ct * 16 + l16;
            size_t base = (size_t)c * kHW + n0 + wave * 32 + rt2 * 16 + quad * 4;
            f32x4 xin = *(const f32x4*)(x_b + base);
            f32x4 y;
#pragma unroll
            for (int r = 0; r < 4; ++r) y[r] = g * acc[rt2][ct][r] * inv[r] + xin[r];
            *(f32x4*)(out_b + base) = y;
        }
    }
}

// ---------------------------------------------------------------------------
extern "C" void kernel_launch(void* const* d_in, const int* in_sizes, int n_in,
                              void* d_out, int out_size, void* d_ws, size_t ws_size,
                              hipStream_t stream) {
    const float* x     = (const float*)d_in[0];
    const float* Wq    = (const float*)d_in[1];
    const float* bq    = (const float*)d_in[2];
    const float* Wk    = (const float*)d_in[3];
    const float* bk    = (const float*)d_in[4];
    const float* Wv    = (const float*)d_in[5];
    const float* bv    = (const float*)d_in[6];
    const float* gamma = (const float*)d_in[7];
    float* out = (float*)d_out;

    char* ws = (char*)d_ws;
    __bf16* XT2h  = (__bf16*)(ws);                 // 16*16*2304*32*2 = 37,748,736
    __bf16* Wqk2h = (__bf16*)(ws + 37748736);      // 16*128*32*2    =    131,072
    __bf16* Wvb2h = (__bf16*)(ws + 37879808);      // 16*512*32*2    =    524,288
    __bf16* qbuf  = (__bf16*)(ws + 38404096);      // 16*2304*64*2   =  4,718,592
    __bf16* kbuf  = (__bf16*)(ws + 43122688);      // 16*72*32*64*2  =  4,718,592
    __bf16* vbuf2 = (__bf16*)(ws + 47841280);      // 16*72*512*40*2 = 47,185,920
    // total = 95,027,200 bytes

    hipLaunchKernelGGL(pack_all, dim3(5632), dim3(256), 0, stream,
                       x, Wq, Wk, Wv, XT2h, Wqk2h, Wvb2h);
    hipLaunchKernelGGL(qkv_gemm, dim3(1440), dim3(256), 0, stream,
                       XT2h, Wqk2h, Wvb2h, bq, bk, bv, qbuf, kbuf, vbuf2);
    hipLaunchKernelGGL(attn_kernel, dim3(1152), dim3(256), 0, stream,
                       qbuf, kbuf, vbuf2, x, gamma, out);
}